// Round 4
// baseline (6318.166 us; speedup 1.0000x reference)
//
#include <hip/hip_runtime.h>
#include <hip/hip_bf16.h>

#define N_USER 100000
#define N_ITEM 200000
#define N_NODE 300000
#define LATDIM 64
#define E_INTER 4000000
#define E_SOC  2000000

#define NODE_ELEMS (N_NODE * LATDIM)   // 19,200,000
#define USER_ELEMS (N_USER * LATDIM)   // 6,400,000

// workspace layout (bytes):
//   accumF32 : float[NODE_ELEMS]      @ 0           76,800,000
//   socCur   : bf16 [USER_ELEMS]      @ 76,800,000  12,800,000
//   fused    : bf16 [5*NODE_ELEMS]    @ 89,600,000 192,000,000
//   total                                          281,600,000  (fits: R2/R3 ran)
// socAccum (float[USER_ELEMS], 25.6 MB) aliases d_out (f32, 76.8 MB, dead
// before final_kernel rewrites all of d_out).
#define WS_REQUIRED 281600000ull

// ---------------------------------------------------------------------------
__global__ __launch_bounds__(256) void zero_f32(float4* __restrict__ p, int n4) {
  int i = blockIdx.x * blockDim.x + threadIdx.x;
  if (i < n4) p[i] = make_float4(0.f, 0.f, 0.f, 0.f);
}

// diagnostic: encode ws_size (MiB) into the output if workspace is short.
__global__ __launch_bounds__(256) void fill_diag(float* __restrict__ o, int n,
                                                 float v) {
  int i = blockIdx.x * blockDim.x + threadIdx.x;
  if (i < n) o[i] = v;
}

// ---------------------------------------------------------------------------
// init: f32 inputs -> f32 inter buffer (ini) and bf16 soc buffer (uEmbeds)
// ---------------------------------------------------------------------------
__global__ __launch_bounds__(256) void init_convert(
    const float* __restrict__ uE, const float* __restrict__ iE,
    float* __restrict__ inter, __hip_bfloat16* __restrict__ soc) {
  int idx = blockIdx.x * blockDim.x + threadIdx.x;
  if (idx >= NODE_ELEMS) return;
  if (idx < USER_ELEMS) {
    float v = uE[idx];
    soc[idx] = __float2bfloat16(v);
    inter[idx] = v;
  } else {
    inter[idx] = iE[idx - USER_ELEMS];
  }
}

// ---------------------------------------------------------------------------
// fuse: one wave per node row.
//   user rows: 2-way gate softmax over concat(soc_row, inter_row) -> mix
//   item rows: pass-through of inter row
// ---------------------------------------------------------------------------
__global__ __launch_bounds__(256) void fuse_kernel(
    const __hip_bfloat16* __restrict__ soc_cur,
    const float* __restrict__ inter_cur,
    const float* __restrict__ W_gate,   // (5,2,128)
    const float* __restrict__ b_gate,   // (5,2)
    int k, __hip_bfloat16* __restrict__ fused_k) {
  int g = blockIdx.x * blockDim.x + threadIdx.x;
  int row = g >> 6;
  int lane = g & 63;
  if (row >= N_NODE) return;
  int off = row * LATDIM + lane;

  if (row < N_USER) {
    float z = __bfloat162float(soc_cur[off]);
    float h = inter_cur[off];
    const float* wg = W_gate + k * 256;
    float p0 = z * wg[lane] + h * wg[64 + lane];
    float p1 = z * wg[128 + lane] + h * wg[192 + lane];
    #pragma unroll
    for (int s = 32; s > 0; s >>= 1) {
      p0 += __shfl_xor(p0, s, 64);
      p1 += __shfl_xor(p1, s, 64);
    }
    p0 += b_gate[k * 2 + 0];
    p1 += b_gate[k * 2 + 1];
    p0 = p0 >= 0.f ? p0 : 0.01f * p0;   // leaky_relu(0.01)
    p1 = p1 >= 0.f ? p1 : 0.01f * p1;
    float mx = fmaxf(p0, p1);
    float e0 = __expf(p0 - mx);
    float e1 = __expf(p1 - mx);
    float inv = 1.f / (e0 + e1);
    float o = z * (e0 * inv) + h * (e1 * inv);
    fused_k[off] = __float2bfloat16(o);
  } else {
    fused_k[off] = __float2bfloat16(inter_cur[off]);
  }
}

// ---------------------------------------------------------------------------
// SpMM (edge-parallel, lane = feature dim): out[row] += val * x[col]
// bf16 gather from internal buffers, f32 atomic accumulate.
// ---------------------------------------------------------------------------
__global__ __launch_bounds__(256) void spmm_kernel(
    const int* __restrict__ rows, const int* __restrict__ cols,
    const float* __restrict__ vals,
    const __hip_bfloat16* __restrict__ x,
    float* __restrict__ out, int nE) {
  unsigned long long g =
      (unsigned long long)blockIdx.x * blockDim.x + threadIdx.x;
  int e = (int)(g >> 6);
  int d = (int)(g & 63);
  if (e >= nE) return;
  int c = cols[e];
  int r = rows[e];
  float v = vals[e];
  float xv = __bfloat162float(x[c * LATDIM + d]);
  unsafeAtomicAdd(out + (r * LATDIM + d), v * xv);
}

// f32 accum -> bf16 store (internal only)
__global__ __launch_bounds__(256) void cvt_f32_bf16(
    const float* __restrict__ src, __hip_bfloat16* __restrict__ dst, int n) {
  int i = blockIdx.x * blockDim.x + threadIdx.x;
  if (i < n) dst[i] = __float2bfloat16(src[i]);
}

// ---------------------------------------------------------------------------
// final: per-row 5-way attention over the 5 fused layers (one wave per row).
// ---------------------------------------------------------------------------
__global__ __launch_bounds__(256) void final_kernel(
    const __hip_bfloat16* __restrict__ fused,
    const float* __restrict__ WL1,     // (5,320)
    const float* __restrict__ bL1,     // (5,)
    const float* __restrict__ WL2,
    const float* __restrict__ bL2,
    float* __restrict__ out) {
  int g = blockIdx.x * blockDim.x + threadIdx.x;
  int row = g >> 6;
  int lane = g & 63;
  if (row >= N_NODE) return;

  float f[5];
  #pragma unroll
  for (int k = 0; k < 5; k++)
    f[k] = __bfloat162float(fused[(size_t)k * NODE_ELEMS + row * LATDIM + lane]);

  const float* WL = (row < N_USER) ? WL1 : WL2;
  const float* bL = (row < N_USER) ? bL1 : bL2;

  float p[5];
  #pragma unroll
  for (int j = 0; j < 5; j++) {
    float s = 0.f;
    #pragma unroll
    for (int k = 0; k < 5; k++)
      s += f[k] * WL[j * 320 + k * 64 + lane];
    p[j] = s;
  }
  #pragma unroll
  for (int s = 32; s > 0; s >>= 1) {
    #pragma unroll
    for (int j = 0; j < 5; j++) p[j] += __shfl_xor(p[j], s, 64);
  }
  float mx = -1e30f;
  #pragma unroll
  for (int j = 0; j < 5; j++) {
    p[j] += bL[j];
    p[j] = p[j] >= 0.f ? p[j] : 0.01f * p[j];
    mx = fmaxf(mx, p[j]);
  }
  float sum = 0.f;
  #pragma unroll
  for (int j = 0; j < 5; j++) {
    p[j] = __expf(p[j] - mx);
    sum += p[j];
  }
  float inv = 1.f / sum;
  float o = 0.f;
  #pragma unroll
  for (int j = 0; j < 5; j++) o += (p[j] * inv) * f[j];
  out[row * LATDIM + lane] = o;
}

// ---------------------------------------------------------------------------
extern "C" void kernel_launch(void* const* d_in, const int* in_sizes, int n_in,
                              void* d_out, int out_size, void* d_ws,
                              size_t ws_size, hipStream_t stream) {
  const float* uE     = (const float*)d_in[0];
  const float* iE     = (const float*)d_in[1];
  const float* W_gate = (const float*)d_in[2];
  const float* b_gate = (const float*)d_in[3];
  const float* WL1    = (const float*)d_in[4];
  const float* bL1    = (const float*)d_in[5];
  const float* WL2    = (const float*)d_in[6];
  const float* bL2    = (const float*)d_in[7];
  const int* inter_rows = (const int*)d_in[8];
  const int* inter_cols = (const int*)d_in[9];
  const float* inter_vals = (const float*)d_in[10];
  const int* soc_rows   = (const int*)d_in[11];
  const int* soc_cols   = (const int*)d_in[12];
  const float* soc_vals = (const float*)d_in[13];
  float* out = (float*)d_out;

  if (ws_size < WS_REQUIRED) {
    float v = (float)(ws_size / (1024ull * 1024ull));
    fill_diag<<<(out_size + 255) / 256, 256, 0, stream>>>(out, out_size, v);
    return;
  }

  float* accumF32 = (float*)d_ws;                              // NODE f32
  __hip_bfloat16* socCur = (__hip_bfloat16*)((char*)d_ws + 76800000);
  __hip_bfloat16* fused  = (__hip_bfloat16*)((char*)d_ws + 89600000);
  float* socAccum = (float*)d_out;                             // 25.6MB scratch

  init_convert<<<NODE_ELEMS / 256, 256, 0, stream>>>(uE, iE, accumF32, socCur);

  for (int k = 0; k < 5; k++) {
    __hip_bfloat16* fk = fused + (size_t)k * NODE_ELEMS;
    fuse_kernel<<<NODE_ELEMS / 256, 256, 0, stream>>>(socCur, accumF32, W_gate,
                                                      b_gate, k, fk);
    if (k < 4) {
      zero_f32<<<NODE_ELEMS / 4 / 256, 256, 0, stream>>>((float4*)accumF32,
                                                         NODE_ELEMS / 4);
      spmm_kernel<<<(int)(((long long)E_INTER * 64) / 256), 256, 0, stream>>>(
          inter_rows, inter_cols, inter_vals, fk, accumF32, E_INTER);
      zero_f32<<<USER_ELEMS / 4 / 256, 256, 0, stream>>>((float4*)socAccum,
                                                         USER_ELEMS / 4);
      spmm_kernel<<<(int)(((long long)E_SOC * 64) / 256), 256, 0, stream>>>(
          soc_rows, soc_cols, soc_vals, socCur, socAccum, E_SOC);
      cvt_f32_bf16<<<USER_ELEMS / 256, 256, 0, stream>>>(socAccum, socCur,
                                                         USER_ELEMS);
    }
  }

  final_kernel<<<NODE_ELEMS / 256, 256, 0, stream>>>(fused, WL1, bL1, WL2, bL2,
                                                     out);
}